// Round 5
// baseline (331.218 us; speedup 1.0000x reference)
//
#include <hip/hip_runtime.h>
#include <hip/hip_bf16.h>

#define B_  2
#define S_  2048
#define H_  24
#define DH_ 32
#define E_  768
#define SW_ (S_/32)   // mask words per row = 64

typedef __attribute__((ext_vector_type(8))) short short8;   // 8 x bf16 bits
typedef __attribute__((ext_vector_type(4))) float f32x4;

static __device__ __forceinline__ short bf16bits(float f) {
    __hip_bfloat16 h = __float2bfloat16(f);
    return *reinterpret_cast<short*>(&h);
}
static __device__ __forceinline__ float bf16tof(short s) {
    __hip_bfloat16 h = *reinterpret_cast<__hip_bfloat16*>(&s);
    return __bfloat162float(h);
}
// 4 floats -> 4 bf16 packed in 8B (2x v_cvt_pk style via __float22bfloat162_rn)
static __device__ __forceinline__ short4 pack4(float a, float b, float c, float d) {
    union { __hip_bfloat162 h[2]; short4 s; } u;
    u.h[0] = __float22bfloat162_rn(make_float2(a, b));
    u.h[1] = __float22bfloat162_rn(make_float2(c, d));
    return u.s;
}
static __device__ __forceinline__ short8 pack8(float4 a, float4 b) {
    union { __hip_bfloat162 h[4]; short8 s; } u;
    u.h[0] = __float22bfloat162_rn(make_float2(a.x, a.y));
    u.h[1] = __float22bfloat162_rn(make_float2(a.z, a.w));
    u.h[2] = __float22bfloat162_rn(make_float2(b.x, b.y));
    u.h[3] = __float22bfloat162_rn(make_float2(b.z, b.w));
    return u.s;
}

// Q is pre-scaled by (1/sqrt(32)) * log2(e): scores come out of MFMA in the
// exp2 domain. Masked branch substitutes -1e-6*log2(e).
#define QSCALE  0.25503487f
#define MLOG2E -1.4426950e-6f

// ---------------------------------------------------------------------------
// Kernel 0a: pack int32 mask -> bitmask via wave ballot.
// ---------------------------------------------------------------------------
__global__ __launch_bounds__(256) void maskpack_kernel(
    const int* __restrict__ mask, unsigned int* __restrict__ mbits)
{
    const int idx  = blockIdx.x * 256 + threadIdx.x;
    const int lane = threadIdx.x & 63;
    const unsigned long long bal = __ballot(mask[idx] != 0);
    if (lane == 0) {
        uint2 w;
        w.x = (unsigned int)(bal & 0xffffffffull);
        w.y = (unsigned int)(bal >> 32);
        *reinterpret_cast<uint2*>(mbits + (idx >> 5)) = w;   // idx 64-aligned
    }
}

// ---------------------------------------------------------------------------
// Kernel 0b: Wo fp32 -> bf16 (one-time)
// ---------------------------------------------------------------------------
__global__ __launch_bounds__(256) void woconv_kernel(
    const float* __restrict__ Wo, __hip_bfloat16* __restrict__ Wob)
{
    const int i = (blockIdx.x * 256 + threadIdx.x) * 4;
    const float4 w = *reinterpret_cast<const float4*>(Wo + i);
    *reinterpret_cast<short4*>(Wob + i) = pack4(w.x, w.y, w.z, w.w);
}

// ---------------------------------------------------------------------------
// Kernel 0c: QKV weights fp32 [h][d][e] -> bf16 transposed [h][e][d].
// This is the MFMA operand layout for BOTH the W^T A-frag (Q^T/K^T compute)
// and the W B-frag (V compute). Tiny (0.3 MB), one block per head.
// ---------------------------------------------------------------------------
__global__ __launch_bounds__(256) void wtprep_kernel(
    const float* __restrict__ Wq, const float* __restrict__ Wk,
    const float* __restrict__ Wv,
    __hip_bfloat16* __restrict__ WTq, __hip_bfloat16* __restrict__ WTk,
    __hip_bfloat16* __restrict__ WTv)
{
    const int h = blockIdx.x;
    const int base = h * DH_ * DH_;
    for (int i = threadIdx.x; i < DH_ * DH_; i += 256) {
        const int d = i >> 5, e = i & 31;
        WTq[base + e * 32 + d] = __float2bfloat16(Wq[base + i]);
        WTk[base + e * 32 + d] = __float2bfloat16(Wk[base + i]);
        WTv[base + e * 32 + d] = __float2bfloat16(Wv[base + i]);
    }
}

// ---------------------------------------------------------------------------
// Kernel 1: MFMA QKV projection. Per wave: 16 s-rows, full 32x32 per-head
// GEMM slice for Q, K, V (6 MFMAs).
//  x-frag (lane: x[s=col][d=quad*8+j], fp32->bf16 packed) serves as:
//    B-operand for Q^T = WTq . x^T  -> lane holds Q[s=col][e=quad*4+r]  (b64!)
//    A-operand for V   = x . WvT    -> lane holds V[s=quad*4+r][e=col]
//      -> Vt[e=col][4 contiguous s] (b64!)
// All stores are packed 8B. grid = (S/64, B*H), block = 256.
// ---------------------------------------------------------------------------
__global__ __launch_bounds__(256) void qkv_kernel(
    const float* __restrict__ x,
    const __hip_bfloat16* __restrict__ WTq,
    const __hip_bfloat16* __restrict__ WTk,
    const __hip_bfloat16* __restrict__ WTv,
    __hip_bfloat16* __restrict__ Qo,
    __hip_bfloat16* __restrict__ Ko,
    __hip_bfloat16* __restrict__ Vto)
{
    const int bh   = blockIdx.y;
    const int b    = bh / H_;
    const int h    = bh - b * H_;
    const int wave = threadIdx.x >> 6;
    const int lane = threadIdx.x & 63;
    const int col  = lane & 15;
    const int quad = lane >> 4;
    const int sw   = blockIdx.x * 64 + wave * 16;   // wave's s base
    const int s    = sw + col;

    const float* xp = x + ((size_t)b * S_ + s) * E_ + h * DH_ + quad * 8;
    const float4 xa = *reinterpret_cast<const float4*>(xp);
    const float4 xb = *reinterpret_cast<const float4*>(xp + 4);
    const short8 xf = pack8(xa, xb);

    const int wofs = h * DH_ * DH_ + col * 32 + quad * 8;
    const short8 aQ0 = *reinterpret_cast<const short8*>(WTq + wofs);
    const short8 aQ1 = *reinterpret_cast<const short8*>(WTq + wofs + 16 * 32);
    const short8 aK0 = *reinterpret_cast<const short8*>(WTk + wofs);
    const short8 aK1 = *reinterpret_cast<const short8*>(WTk + wofs + 16 * 32);
    const short8 bV0 = *reinterpret_cast<const short8*>(WTv + wofs);
    const short8 bV1 = *reinterpret_cast<const short8*>(WTv + wofs + 16 * 32);

    const f32x4 z = {0.f, 0.f, 0.f, 0.f};
    const f32x4 qt0 = __builtin_amdgcn_mfma_f32_16x16x32_bf16(aQ0, xf, z, 0, 0, 0);
    const f32x4 qt1 = __builtin_amdgcn_mfma_f32_16x16x32_bf16(aQ1, xf, z, 0, 0, 0);
    const f32x4 kt0 = __builtin_amdgcn_mfma_f32_16x16x32_bf16(aK0, xf, z, 0, 0, 0);
    const f32x4 kt1 = __builtin_amdgcn_mfma_f32_16x16x32_bf16(aK1, xf, z, 0, 0, 0);
    const f32x4 vv0 = __builtin_amdgcn_mfma_f32_16x16x32_bf16(xf, bV0, z, 0, 0, 0);
    const f32x4 vv1 = __builtin_amdgcn_mfma_f32_16x16x32_bf16(xf, bV1, z, 0, 0, 0);

    __hip_bfloat16* qrow = Qo + ((size_t)bh * S_ + s) * DH_;
    *reinterpret_cast<short4*>(qrow + quad * 4) =
        pack4(qt0[0] * QSCALE, qt0[1] * QSCALE, qt0[2] * QSCALE, qt0[3] * QSCALE);
    *reinterpret_cast<short4*>(qrow + 16 + quad * 4) =
        pack4(qt1[0] * QSCALE, qt1[1] * QSCALE, qt1[2] * QSCALE, qt1[3] * QSCALE);

    __hip_bfloat16* krow = Ko + ((size_t)bh * S_ + s) * DH_;
    *reinterpret_cast<short4*>(krow + quad * 4)      = pack4(kt0[0], kt0[1], kt0[2], kt0[3]);
    *reinterpret_cast<short4*>(krow + 16 + quad * 4) = pack4(kt1[0], kt1[1], kt1[2], kt1[3]);

    const int sb = sw + quad * 4;   // V rows: s = sb..sb+3
    *reinterpret_cast<short4*>(Vto + ((size_t)bh * DH_ + col) * S_ + sb) =
        pack4(vv0[0], vv0[1], vv0[2], vv0[3]);
    *reinterpret_cast<short4*>(Vto + ((size_t)bh * DH_ + 16 + col) * S_ + sb) =
        pack4(vv1[0], vv1[1], vv1[2], vv1[3]);
}

// ---------------------------------------------------------------------------
// Kernel 2: fused attention v4 — TRANSPOSED dataflow.
//   S^T = K.Q^T  : A = K-frag (unchanged load), B = Q-frag (same layout as
//                  old A-frag!). Lane holds P[q=col][key=quad*4+r] per set.
//   -> ONE mask word per lane per iter (row q=col), 8 bit-tests.
//   -> P repack: 2 packed ds_write_b64 (4 contiguous keys) + 4 cvt_pk.
//   O^T = Vt.P^T : A = Vt-frag (unchanged load), B = P from LDS (b128).
//                  Lane holds O[q=col][d=quad*4+r] -> packed b64 epilogue.
// Q pre-scaled into exp2 domain; raw v_exp_f32 via __builtin_amdgcn_exp2f.
// Split-K over gridDim.z (O,l additive; |scores| ~ O(1), no running max).
// grid = (S/64, B*H, parts), block = 256 (4 waves x 16 q-rows)
// ---------------------------------------------------------------------------
__global__ __launch_bounds__(256) void attn_kernel(
    const __hip_bfloat16* __restrict__ Q,     // [B*H][S][DH] (pre-scaled)
    const __hip_bfloat16* __restrict__ K,     // [B*H][S][DH]
    const __hip_bfloat16* __restrict__ Vt,    // [B*H][DH][S]
    const unsigned int* __restrict__ mbits,   // [B][S][S/32]
    __hip_bfloat16* __restrict__ Opart,       // [parts][B][S][E] unnormalized
    float* __restrict__ lpart)                // [parts][B*H][S]
{
    const int bh   = blockIdx.y;
    const int b    = bh / H_;
    const int h    = bh - b * H_;
    const int part = blockIdx.z;
    const int nkey = S_ / gridDim.z;
    const int kbeg = part * nkey;
    const int wave = threadIdx.x >> 6;
    const int lane = threadIdx.x & 63;
    const int col  = lane & 15;
    const int quad = lane >> 4;
    const int q0   = blockIdx.x * 64 + wave * 16;

    const __hip_bfloat16* Qbh = Q  + (size_t)bh * S_ * DH_;
    const __hip_bfloat16* Kbh = K  + (size_t)bh * S_ * DH_;
    const __hip_bfloat16* Vbh = Vt + (size_t)bh * DH_ * S_;

    // Q B-frag (lane: Q[q=col][d=quad*8..+7]) — loaded once
    const short8 qfrag =
        *reinterpret_cast<const short8*>(Qbh + (size_t)(q0 + col) * DH_ + quad * 8);

    // running pointers (strength-reduced addressing)
    const __hip_bfloat16* Kp  = Kbh + (size_t)(kbeg + col) * DH_ + quad * 8;
    const __hip_bfloat16* Vp0 = Vbh + (size_t)col * S_ + kbeg + quad * 8;
    const __hip_bfloat16* Vp1 = Vbh + (size_t)(16 + col) * S_ + kbeg + quad * 8;
    const unsigned int*   mp  = mbits + (size_t)b * S_ * SW_
                              + (size_t)(q0 + col) * SW_ + (kbeg >> 5);

    f32x4 o0 = {0.f,0.f,0.f,0.f};   // O[q=col][d=quad*4+r]
    f32x4 o1 = {0.f,0.f,0.f,0.f};   // O[q=col][d=16+quad*4+r]
    float lsum = 0.f;               // partial l[q=col]

    __shared__ __align__(16) __hip_bfloat16 pbuf[2][4][16][40];  // dbuf 10.2KB

    const int niter = nkey >> 5;
    for (int it = 0; it < niter; ++it) {
        const unsigned int mw = *mp;
        const short8 kf0 = *reinterpret_cast<const short8*>(Kp);
        const short8 kf1 = *reinterpret_cast<const short8*>(Kp + 16 * DH_);
        const short8 vf0 = *reinterpret_cast<const short8*>(Vp0);
        const short8 vf1 = *reinterpret_cast<const short8*>(Vp1);

        const f32x4 z = {0.f, 0.f, 0.f, 0.f};
        // S^T: lane reg r = P[q=col][key = (it*32) + quad*4+r (+16 for s1)]
        const f32x4 s0 = __builtin_amdgcn_mfma_f32_16x16x32_bf16(kf0, qfrag, z, 0, 0, 0);
        const f32x4 s1 = __builtin_amdgcn_mfma_f32_16x16x32_bf16(kf1, qfrag, z, 0, 0, 0);

        float p0[4], p1[4];
#pragma unroll
        for (int r = 0; r < 4; ++r) {
            const int kb = quad * 4 + r;
            const float t0 = ((mw >> kb)        & 1u) ? s0[r] : MLOG2E;
            const float t1 = ((mw >> (16 + kb)) & 1u) ? s1[r] : MLOG2E;
            p0[r] = __builtin_amdgcn_exp2f(t0);
            p1[r] = __builtin_amdgcn_exp2f(t1);
        }
        lsum += ((p0[0] + p0[1]) + (p0[2] + p0[3]))
              + ((p1[0] + p1[1]) + (p1[2] + p1[3]));

        __hip_bfloat16 (*pb)[40] = pbuf[it & 1][wave];
        *reinterpret_cast<short4*>(&pb[col][quad * 4]) =
            pack4(p0[0], p0[1], p0[2], p0[3]);
        *reinterpret_cast<short4*>(&pb[col][16 + quad * 4]) =
            pack4(p1[0], p1[1], p1[2], p1[3]);

        // P^T B-frag: lane reads P[q=col][key=quad*8..+7] (in-wave DS ordered)
        const short8 pfrag = *reinterpret_cast<const short8*>(&pb[col][quad * 8]);

        o0 = __builtin_amdgcn_mfma_f32_16x16x32_bf16(vf0, pfrag, o0, 0, 0, 0);
        o1 = __builtin_amdgcn_mfma_f32_16x16x32_bf16(vf1, pfrag, o1, 0, 0, 0);

        Kp  += 32 * DH_;
        Vp0 += 32;
        Vp1 += 32;
        mp  += 1;
    }

    // reduce l across quads (lanes col, col+16, col+32, col+48)
    lsum += __shfl_xor(lsum, 16);
    lsum += __shfl_xor(lsum, 32);

    __hip_bfloat16* orow = Opart + (size_t)part * B_ * S_ * E_
                         + ((size_t)b * S_ + q0 + col) * E_ + h * DH_;
    *reinterpret_cast<short4*>(orow + quad * 4)      = pack4(o0[0], o0[1], o0[2], o0[3]);
    *reinterpret_cast<short4*>(orow + 16 + quad * 4) = pack4(o1[0], o1[1], o1[2], o1[3]);
    if (quad == 0)
        lpart[((size_t)part * B_ * H_ + bh) * S_ + q0 + col] = lsum;
}

// ---------------------------------------------------------------------------
// Kernel 2b: combine split-K partials: att = (sum_p O_p) / (sum_p l_p), bf16.
// In-place safe when Opart aliases att (parts==1).
// ---------------------------------------------------------------------------
__global__ __launch_bounds__(256) void combine_kernel(
    const __hip_bfloat16* __restrict__ Opart,
    const float* __restrict__ lpart,
    __hip_bfloat16* __restrict__ att,
    int parts)
{
    const size_t idx4 = ((size_t)blockIdx.x * 256 + threadIdx.x) * 4;
    const int e  = (int)(idx4 % E_);
    const size_t bs = idx4 / E_;
    const int h  = e >> 5;
    const int b  = (int)(bs / S_);
    const int s  = (int)(bs % S_);

    float a0 = 0.f, a1 = 0.f, a2 = 0.f, a3 = 0.f, l = 0.f;
    for (int p = 0; p < parts; ++p) {
        const short4 ov = *reinterpret_cast<const short4*>(
            Opart + (size_t)p * B_ * S_ * E_ + idx4);
        a0 += bf16tof(ov.x); a1 += bf16tof(ov.y);
        a2 += bf16tof(ov.z); a3 += bf16tof(ov.w);
        l += lpart[((size_t)p * B_ * H_ + b * H_ + h) * S_ + s];
    }
    const float linv = 1.0f / l;
    *reinterpret_cast<short4*>(att + idx4) =
        pack4(a0 * linv, a1 * linv, a2 * linv, a3 * linv);
}

// ---------------------------------------------------------------------------
// Kernel 3: output projection, bf16 Wo. Wave: 32 m x 64 n.
// grid = (M/32, 768/256), block = 256.
// ---------------------------------------------------------------------------
__global__ __launch_bounds__(256) void proj_kernel(
    const __hip_bfloat16* __restrict__ A,     // [4096][768] bf16 (ws)
    const __hip_bfloat16* __restrict__ Wob,   // [768][768] bf16 (ws)
    const float* __restrict__ bo,             // [768] fp32
    float* __restrict__ out)                  // [4096][768] fp32
{
    const int wave = threadIdx.x >> 6;
    const int lane = threadIdx.x & 63;
    const int col  = lane & 15;
    const int quad = lane >> 4;
    const int m0   = blockIdx.x * 32;
    const int n0   = blockIdx.y * 256 + wave * 64;

    f32x4 acc[2][4] = {{{0.f,0.f,0.f,0.f},{0.f,0.f,0.f,0.f},
                        {0.f,0.f,0.f,0.f},{0.f,0.f,0.f,0.f}},
                       {{0.f,0.f,0.f,0.f},{0.f,0.f,0.f,0.f},
                        {0.f,0.f,0.f,0.f},{0.f,0.f,0.f,0.f}}};
    for (int k0 = 0; k0 < E_; k0 += 32) {
        const short8 af0 = *reinterpret_cast<const short8*>(
            A + (size_t)(m0 + col) * E_ + k0 + quad * 8);
        const short8 af1 = *reinterpret_cast<const short8*>(
            A + (size_t)(m0 + 16 + col) * E_ + k0 + quad * 8);
#pragma unroll
        for (int j = 0; j < 4; ++j) {
            const short8 bf = *reinterpret_cast<const short8*>(
                Wob + (size_t)(n0 + j * 16 + col) * E_ + k0 + quad * 8);
            acc[0][j] = __builtin_amdgcn_mfma_f32_16x16x32_bf16(af0, bf, acc[0][j], 0, 0, 0);
            acc[1][j] = __builtin_amdgcn_mfma_f32_16x16x32_bf16(af1, bf, acc[1][j], 0, 0, 0);
        }
    }
#pragma unroll
    for (int j = 0; j < 4; ++j) {
        const int n = n0 + j * 16 + col;
        const float bias = bo[n];
#pragma unroll
        for (int mi = 0; mi < 2; ++mi) {
#pragma unroll
            for (int r = 0; r < 4; ++r) {
                const int m = m0 + mi * 16 + quad * 4 + r;
                out[(size_t)m * E_ + n] = acc[mi][j][r] + bias;
            }
        }
    }
}

// ---------------------------------------------------------------------------
extern "C" void kernel_launch(void* const* d_in, const int* in_sizes, int n_in,
                              void* d_out, int out_size, void* d_ws, size_t ws_size,
                              hipStream_t stream)
{
    const float* emb = (const float*)d_in[0];
    const int*   msk = (const int*)d_in[1];
    const float* Wq  = (const float*)d_in[2];
    const float* Wk  = (const float*)d_in[3];
    const float* Wv  = (const float*)d_in[4];
    const float* Wo  = (const float*)d_in[5];
    const float* bo  = (const float*)d_in[6];
    float* out = (float*)d_out;

    const size_t nqkv = (size_t)B_ * H_ * S_ * DH_;   // 3,145,728 (= B*S*E)
    char* p = (char*)d_ws;
    __hip_bfloat16* Q    = (__hip_bfloat16*)p;  p += nqkv * 2;
    __hip_bfloat16* Kp   = (__hip_bfloat16*)p;  p += nqkv * 2;
    __hip_bfloat16* Vt   = (__hip_bfloat16*)p;  p += nqkv * 2;
    __hip_bfloat16* att  = (__hip_bfloat16*)p;  p += nqkv * 2;
    unsigned int*  mbits = (unsigned int*)p;    p += (size_t)B_ * S_ * SW_ * 4;
    __hip_bfloat16* Wob  = (__hip_bfloat16*)p;  p += (size_t)E_ * E_ * 2;
    __hip_bfloat16* WTq  = (__hip_bfloat16*)p;  p += (size_t)H_ * DH_ * DH_ * 2;
    __hip_bfloat16* WTk  = (__hip_bfloat16*)p;  p += (size_t)H_ * DH_ * DH_ * 2;
    __hip_bfloat16* WTv  = (__hip_bfloat16*)p;  p += (size_t)H_ * DH_ * DH_ * 2;
    const size_t base = (size_t)(p - (char*)d_ws);

    __hip_bfloat16* Opart = (__hip_bfloat16*)p;
    float* lpart;
    int parts = 1;
    for (int cand = 4; cand >= 2; cand >>= 1) {
        const size_t need = base + (size_t)cand * nqkv * 2
                          + (size_t)cand * B_ * H_ * S_ * 4;
        if (ws_size >= need) { parts = cand; break; }
    }
    if (parts > 1) {
        lpart = (float*)(p + (size_t)parts * nqkv * 2);
    } else {
        Opart = att;                 // write unnormalized into att;
        lpart = (float*)p;           // combine normalizes in-place
    }

    maskpack_kernel<<<(B_ * S_ * S_) / 256, 256, 0, stream>>>(msk, mbits);
    woconv_kernel  <<<(E_ * E_) / 1024,     256, 0, stream>>>(Wo, Wob);
    wtprep_kernel  <<<H_,                   256, 0, stream>>>(Wq, Wk, Wv, WTq, WTk, WTv);
    qkv_kernel <<<dim3(S_ / 64, B_ * H_), 256, 0, stream>>>(emb, WTq, WTk, WTv, Q, Kp, Vt);
    attn_kernel<<<dim3(S_ / 64, B_ * H_, parts), 256, 0, stream>>>(Q, Kp, Vt, mbits, Opart, lpart);
    combine_kernel<<<(B_ * S_ * E_) / 1024, 256, 0, stream>>>(Opart, lpart, att, parts);
    proj_kernel<<<dim3((B_ * S_) / 32, E_ / 256), 256, 0, stream>>>(att, Wob, bo, out);
}